// Round 5
// baseline (160.778 us; speedup 1.0000x reference)
//
#include <hip/hip_runtime.h>
#include <math.h>

#define DIM  768
#define NH   12
#define HD   64
#define NQ   2048
#define NKV  2048
// QSCALE * log2(e) folded into Q projection epilogue
#define QSC_LOG2E 0.18033688011112042f

typedef short bf16x8  __attribute__((ext_vector_type(8)));
typedef float f32x4   __attribute__((ext_vector_type(4)));
typedef float f32x16  __attribute__((ext_vector_type(16)));

__device__ __forceinline__ unsigned short f2bf(float f) {
    unsigned u = __float_as_uint(f);
    unsigned r = (u + 0x7FFFu + ((u >> 16) & 1u)) >> 16;
    return (unsigned short)r;
}
__device__ __forceinline__ float bf2f(unsigned short u) {
    return __uint_as_float(((unsigned)u) << 16);
}

__device__ __forceinline__ unsigned cvtpk_bf16(float a, float b) {
    unsigned r;
    asm("v_cvt_pk_bf16_f32 %0, %1, %2" : "=v"(r) : "v"(a), "v"(b));
    return r;   // lo = bf16(a), hi = bf16(b)
}

// v_permlane32_swap_b32 vdst, vsrc: vdst[32..63] <-> vsrc[0..31].
__device__ __forceinline__ void plswap(unsigned& a, unsigned& b) {
    asm("v_permlane32_swap_b32 %0, %1" : "+v"(a), "+v"(b));
}

__device__ __forceinline__ float vexp2f(float x) {
#if __has_builtin(__builtin_amdgcn_exp2f)
    return __builtin_amdgcn_exp2f(x);
#else
    float r;
    asm("v_exp_f32 %0, %1\ns_nop 0" : "=v"(r) : "v"(x));
    return r;
#endif
}

__device__ __forceinline__ void ld_lds16(void* lds, const void* g) {
    __builtin_amdgcn_global_load_lds(
        (const __attribute__((address_space(1))) unsigned int*)g,
        (__attribute__((address_space(3))) unsigned int*)lds, 16, 0, 0);
}

__device__ __forceinline__ f32x16 z16() {
    f32x16 r;
    #pragma unroll
    for (int e = 0; e < 16; ++e) r[e] = 0.f;
    return r;
}

union PB16 { unsigned u[4]; bf16x8 v; };

// ---------------------------------------------------------------------------
// kc = latent_k @ Wk_c  (fp32), grid 48 x 256
// ---------------------------------------------------------------------------
__global__ __launch_bounds__(256)
void kc2_kernel(const float* __restrict__ latent, const float* __restrict__ Wkc,
                float* __restrict__ kc) {
    __shared__ float red[16][17];
    int tx = threadIdx.x & 15, ty = threadIdx.x >> 4;
    int j = blockIdx.x * 16 + tx;
    float acc = 0.f;
    for (int i = ty * 48; i < ty * 48 + 48; ++i) acc += latent[i] * Wkc[i * DIM + j];
    red[ty][tx] = acc;
    __syncthreads();
    if (ty == 0) {
        float s = 0.f;
        #pragma unroll
        for (int k = 0; k < 16; ++k) s += red[k][tx];
        kc[j] = s;
    }
}

// ---------------------------------------------------------------------------
// fp32 -> bf16, up to 4 tensors into consecutive slabs of dstA
// ---------------------------------------------------------------------------
__global__ __launch_bounds__(256)
void convert_acts(const float* __restrict__ s0, const float* __restrict__ s1,
                  const float* __restrict__ s2, const float* __restrict__ s3,
                  unsigned short* __restrict__ dstA) {
    const float* srcs[4] = {s0, s1, s2, s3};
    int y = blockIdx.y;
    const float* s = srcs[y];
    unsigned short* d = dstA + (size_t)y * 3145728;
    size_t i = ((size_t)blockIdx.x * 256 + threadIdx.x) * 4;
    float4 v = *(const float4*)(s + i);
    ushort4 o;
    o.x = f2bf(v.x); o.y = f2bf(v.y); o.z = f2bf(v.z); o.w = f2bf(v.w);
    *(ushort4*)(d + i) = o;
}

// ---------------------------------------------------------------------------
// weight transpose+convert: W fp32 [768][768] -> Wt bf16 [n][k]
// ---------------------------------------------------------------------------
__global__ __launch_bounds__(256)
void conv_w(const float* __restrict__ w0, const float* __restrict__ w1,
            const float* __restrict__ w2, const float* __restrict__ w3,
            const float* __restrict__ w4, const float* __restrict__ w5,
            const float* __restrict__ w6, unsigned short* __restrict__ dst) {
    __shared__ float t[32][33];
    const float* Ws[7] = {w0, w1, w2, w3, w4, w5, w6};
    const float* W = Ws[blockIdx.z];
    unsigned short* D = dst + (size_t)blockIdx.z * (768 * 768);
    int r0 = blockIdx.y * 32, c0 = blockIdx.x * 32;
    int tx = threadIdx.x & 31, ty = threadIdx.x >> 5;
    #pragma unroll
    for (int yy = 0; yy < 4; ++yy)
        t[ty * 4 + yy][tx] = W[(size_t)(r0 + ty * 4 + yy) * 768 + c0 + tx];
    __syncthreads();
    #pragma unroll
    for (int yy = 0; yy < 4; ++yy)
        D[(size_t)(c0 + ty * 4 + yy) * 768 + r0 + tx] = f2bf(t[tx][ty * 4 + yy]);
}

// ---------------------------------------------------------------------------
// MFMA GEMM core, 2-phase dbuf, runtime config. Tile 64(M)x128(N), BK=64.
// mode: 0 bf16 out (+opt fp32 bias), 1 f32 out +bias, 2 bf16 out *scale,
//       3 bf16 transposed out into Vt[b][768][2048]
// Launched with grid (6, 64, nz); z selects cfg; nblk = 384*nz for XCD swizzle.
// ---------------------------------------------------------------------------
struct GemmCfg {
    const unsigned short* A0; const unsigned short* A1; const unsigned short* A2;
    const unsigned short* B0; const unsigned short* B1; const unsigned short* B2;
    const float* bias; float scale; void* out; int npair; int mode;
};

__global__ __launch_bounds__(256)
void gemm_any(GemmCfg c0, GemmCfg c1, int nblk) {
    __shared__ unsigned short As[2][64 * 64];    // 2 x 8 KB
    __shared__ unsigned short Bs[2][128 * 64];   // 2 x 16 KB
    const int tid = threadIdx.x;
    const int w = tid >> 6, l = tid & 63, g = l >> 4, r16 = l & 15;

    // XCD-bijective swizzle over the whole (possibly fused) grid
    int o_lin = blockIdx.x + 6 * blockIdx.y + 384 * blockIdx.z;
    int per = nblk >> 3;
    int wl = (o_lin & 7) * per + (o_lin >> 3);
    int zz = wl / 384, rem = wl - zz * 384;
    int bx = rem % 6, by = rem / 6;
    const int n0 = bx * 128, m0 = by * 64;

    const unsigned short* Alist[3];
    const unsigned short* Blist[3];
    const float* bias; float scale; void* Cout; int npair, mode;
    if (zz == 0) {
        Alist[0] = c0.A0; Alist[1] = c0.A1; Alist[2] = c0.A2;
        Blist[0] = c0.B0; Blist[1] = c0.B1; Blist[2] = c0.B2;
        bias = c0.bias; scale = c0.scale; Cout = c0.out;
        npair = c0.npair; mode = c0.mode;
    } else {
        Alist[0] = c1.A0; Alist[1] = c1.A1; Alist[2] = c1.A2;
        Blist[0] = c1.B0; Blist[1] = c1.B1; Blist[2] = c1.B2;
        bias = c1.bias; scale = c1.scale; Cout = c1.out;
        npair = c1.npair; mode = c1.mode;
    }

    f32x4 acc[4][2];
    #pragma unroll
    for (int i = 0; i < 4; ++i)
        #pragma unroll
        for (int j = 0; j < 2; ++j) acc[i][j] = (f32x4){0.f, 0.f, 0.f, 0.f};

#define GSTAGE(BUFI, AP, BP, K0) { \
    _Pragma("unroll") \
    for (int is = 0; is < 2; ++is) { \
        int u = is * 256 + tid, r = u >> 3, cc = u & 7; \
        int col = ((cc ^ (r & 7)) << 3); \
        ld_lds16((char*)As[BUFI] + is * 4096 + w * 1024, \
                 (AP) + (size_t)(m0 + r) * 768 + (K0) + col); } \
    _Pragma("unroll") \
    for (int is = 0; is < 4; ++is) { \
        int u = is * 256 + tid, r = u >> 3, cc = u & 7; \
        int col = ((cc ^ (r & 7)) << 3); \
        ld_lds16((char*)Bs[BUFI] + is * 4096 + w * 1024, \
                 (BP) + (size_t)(n0 + r) * 768 + (K0) + col); } }

    const int NSTEPS = npair * 12;
    int pn = 0, kn = 0;           // indices of the NEXT step to stage
    GSTAGE(0, Alist[0], Blist[0], 0);
    kn = 64;
    __syncthreads();

    #pragma unroll 1
    for (int st = 0; st < NSTEPS; ++st) {
        int cur = st & 1;
        if (st + 1 < NSTEPS) {
            GSTAGE(cur ^ 1, Alist[pn], Blist[pn], kn);
            kn += 64; if (kn == 768) { kn = 0; ++pn; }
        }
        const char* Ab = (const char*)As[cur];
        const char* Bb = (const char*)Bs[cur];
        #pragma unroll
        for (int kk = 0; kk < 2; ++kk) {
            bf16x8 af[4], bf[2];
            #pragma unroll
            for (int i = 0; i < 4; ++i) {
                int row = i * 16 + r16;
                af[i] = *(const bf16x8*)(Ab + row * 128 +
                          ((kk * 64 + g * 16) ^ ((row & 7) << 4)));
            }
            #pragma unroll
            for (int j = 0; j < 2; ++j) {
                int row = w * 32 + j * 16 + r16;
                bf[j] = *(const bf16x8*)(Bb + row * 128 +
                          ((kk * 64 + g * 16) ^ ((row & 7) << 4)));
            }
            #pragma unroll
            for (int i = 0; i < 4; ++i)
                #pragma unroll
                for (int j = 0; j < 2; ++j)
                    acc[i][j] = __builtin_amdgcn_mfma_f32_16x16x32_bf16(
                        af[i], bf[j], acc[i][j], 0, 0, 0);
        }
        __syncthreads();
    }
#undef GSTAGE

    #pragma unroll
    for (int i = 0; i < 4; ++i) {
        #pragma unroll
        for (int j = 0; j < 2; ++j) {
            int col = n0 + w * 32 + j * 16 + r16;
            float bv = ((mode == 0 && bias) || mode == 1) ? bias[col] : 0.f;
            #pragma unroll
            for (int rr = 0; rr < 4; ++rr) {
                int row = m0 + i * 16 + g * 4 + rr;
                float v = acc[i][j][rr];
                if (mode == 2) v *= scale;
                v += bv;
                if (mode == 1) {
                    ((float*)Cout)[(size_t)row * 768 + col] = v;
                } else if (mode == 3) {
                    int bb = row >> 11, q = row & 2047;
                    ((unsigned short*)Cout)[(size_t)(bb * 768 + col) * 2048 + q] = f2bf(v);
                } else {
                    ((unsigned short*)Cout)[(size_t)row * 768 + col] = f2bf(v);
                }
            }
        }
    }
}

// ---------------------------------------------------------------------------
// Flash attention, split-KV 2-way. grid (32, 24): x = qi(0..15) | part<<4,
// y = bh. Each block: 128 q rows x 1024 kv. Emits unnormalized partial
// O^T bf16 [bh][64 d][2048 q] per part + (m,l) f32 per q-row.
// ---------------------------------------------------------------------------
__global__ __launch_bounds__(256)
void flash2(const unsigned short* __restrict__ Qb,
            const unsigned short* __restrict__ Kb,
            const unsigned short* __restrict__ Vt,
            unsigned short* __restrict__ P0,
            unsigned short* __restrict__ P1,
            float2* __restrict__ ML) {
    __shared__ unsigned short KV[2][2][4096];  // [buf][K|Vt][64*64], 32 KB
    const int tid = threadIdx.x;
    const int w = tid >> 6, l = tid & 63, lo = l & 31, hi = l >> 5;

    // XCD-bijective swizzle: 768 blocks = 8 * 96
    int o_lin = blockIdx.x + 32 * blockIdx.y;
    int wl = (o_lin & 7) * 96 + (o_lin >> 3);
    int qi = wl & 15, part = (wl >> 4) & 1, bh = wl >> 5;
    int b = bh / NH, h = bh % NH;
    int q0 = qi * 128;
    int kvbase = part * 1024;

    // Q B-fragments, scaled upstream by QSC_LOG2E
    bf16x8 qf[4];
    {
        const unsigned short* Qrow =
            Qb + (size_t)(b * NQ + q0 + w * 32 + lo) * DIM + h * HD + hi * 8;
        #pragma unroll
        for (int kc = 0; kc < 4; ++kc) qf[kc] = *(const bf16x8*)(Qrow + kc * 16);
    }

    f32x16 o0 = z16(), o1 = z16();
    float m = -3.0e38f, lsum = 0.f;

    const unsigned short* Kbase = Kb + (size_t)(b * NKV) * DIM + h * HD;
    const unsigned short* Vbase = Vt + ((size_t)b * DIM + h * HD) * NKV;

#define FSTAGE(BUFI, T0) { \
    _Pragma("unroll") \
    for (int is = 0; is < 2; ++is) { \
        int u = is * 256 + tid, r = u >> 3, cc = u & 7; \
        int col = ((cc ^ (r & 7)) << 3); \
        ld_lds16((char*)KV[BUFI][0] + is * 4096 + w * 1024, \
                 Kbase + (size_t)((T0) + r) * 768 + col); \
        ld_lds16((char*)KV[BUFI][1] + is * 4096 + w * 1024, \
                 Vbase + (size_t)r * 2048 + (T0) + col); } }

    FSTAGE(0, kvbase);
    __syncthreads();

    #pragma unroll 1
    for (int t = 0; t < 16; ++t) {
        int cur = t & 1;
        if (t < 15) FSTAGE(cur ^ 1, kvbase + (t + 1) * 64);

        const char* Kp = (const char*)KV[cur][0];
        const char* Vp = (const char*)KV[cur][1];

        // S^T = K . Q^T : lane owns one q-row, 32 kv values
        f32x16 s0 = z16(), s1 = z16();
        #pragma unroll
        for (int kc = 0; kc < 4; ++kc) {
            int r0 = lo, r1 = 32 + lo;
            bf16x8 k0 = *(const bf16x8*)(Kp + r0 * 128 +
                          ((kc * 32 + hi * 16) ^ ((r0 & 7) << 4)));
            bf16x8 k1 = *(const bf16x8*)(Kp + r1 * 128 +
                          ((kc * 32 + hi * 16) ^ ((r1 & 7) << 4)));
            s0 = __builtin_amdgcn_mfma_f32_32x32x16_bf16(k0, qf[kc], s0, 0, 0, 0);
            s1 = __builtin_amdgcn_mfma_f32_32x32x16_bf16(k1, qf[kc], s1, 0, 0, 0);
        }

        // in-register softmax (log2 domain), lane pair (l, l^32) shares a q-row
        float a8[8];
        #pragma unroll
        for (int e = 0; e < 8; ++e)
            a8[e] = fmaxf(fmaxf(s0[e], s0[e + 8]), fmaxf(s1[e], s1[e + 8]));
        #pragma unroll
        for (int e = 0; e < 4; ++e) a8[e] = fmaxf(a8[e], a8[e + 4]);
        float pm = fmaxf(fmaxf(a8[0], a8[1]), fmaxf(a8[2], a8[3]));
        pm = fmaxf(pm, __shfl_xor(pm, 32));

        if (__any(pm > m + 10.f)) {           // defer-max (T13)
            float mn = fmaxf(m, pm);
            float sc = vexp2f(m - mn);
            lsum *= sc;
            #pragma unroll
            for (int e = 0; e < 16; ++e) { o0[e] *= sc; o1[e] *= sc; }
            m = mn;
        }

        #pragma unroll
        for (int e = 0; e < 16; ++e) {
            s0[e] = vexp2f(s0[e] - m);
            s1[e] = vexp2f(s1[e] - m);
        }

        float b8[8];
        #pragma unroll
        for (int e = 0; e < 8; ++e)
            b8[e] = (s0[e] + s0[e + 8]) + (s1[e] + s1[e + 8]);
        float rs = ((b8[0] + b8[1]) + (b8[2] + b8[3])) +
                   ((b8[4] + b8[5]) + (b8[6] + b8[7]));
        rs += __shfl_xor(rs, 32);
        lsum += rs;

        // P -> bf16 B-fragments via cvt_pk + permlane32_swap
        PB16 pb[4];
        #pragma unroll
        for (int cc = 0; cc < 2; ++cc) {
            unsigned a0 = cvtpk_bf16(s0[cc * 8 + 0], s0[cc * 8 + 1]);
            unsigned a1 = cvtpk_bf16(s0[cc * 8 + 2], s0[cc * 8 + 3]);
            unsigned b0 = cvtpk_bf16(s0[cc * 8 + 4], s0[cc * 8 + 5]);
            unsigned b1 = cvtpk_bf16(s0[cc * 8 + 6], s0[cc * 8 + 7]);
            plswap(a0, b0);
            plswap(a1, b1);
            pb[cc].u[0] = a0; pb[cc].u[1] = a1; pb[cc].u[2] = b0; pb[cc].u[3] = b1;
            unsigned c0 = cvtpk_bf16(s1[cc * 8 + 0], s1[cc * 8 + 1]);
            unsigned c1 = cvtpk_bf16(s1[cc * 8 + 2], s1[cc * 8 + 3]);
            unsigned d0 = cvtpk_bf16(s1[cc * 8 + 4], s1[cc * 8 + 5]);
            unsigned d1 = cvtpk_bf16(s1[cc * 8 + 6], s1[cc * 8 + 7]);
            plswap(c0, d0);
            plswap(c1, d1);
            pb[2 + cc].u[0] = c0; pb[2 + cc].u[1] = c1;
            pb[2 + cc].u[2] = d0; pb[2 + cc].u[3] = d1;
        }

        // O^T += V^T . P^T
        #pragma unroll
        for (int c = 0; c < 4; ++c) {
            int r0 = lo, r1 = 32 + lo;
            bf16x8 v0 = *(const bf16x8*)(Vp + r0 * 128 +
                          ((c * 32 + hi * 16) ^ ((r0 & 7) << 4)));
            bf16x8 v1 = *(const bf16x8*)(Vp + r1 * 128 +
                          ((c * 32 + hi * 16) ^ ((r1 & 7) << 4)));
            o0 = __builtin_amdgcn_mfma_f32_32x32x16_bf16(v0, pb[c].v, o0, 0, 0, 0);
            o1 = __builtin_amdgcn_mfma_f32_32x32x16_bf16(v1, pb[c].v, o1, 0, 0, 0);
        }
        __syncthreads();
    }
#undef FSTAGE

    // store unnormalized partial O^T (bf16) + (m, l)
    unsigned short* Op = (part ? P1 : P0) + (size_t)bh * 64 * 2048;
    int q = q0 + w * 32 + lo;
    #pragma unroll
    for (int r = 0; r < 16; ++r) {
        int d0 = (r & 3) + 8 * (r >> 2) + 4 * hi;
        Op[(size_t)d0 * 2048 + q] = f2bf(o0[r]);
        Op[(size_t)(32 + d0) * 2048 + q] = f2bf(o1[r]);
    }
    if (hi == 0)
        ML[(size_t)(part * 24 + bh) * 2048 + q] = make_float2(m, lsum);
}

// ---------------------------------------------------------------------------
// combine: AO[b][q][h*64+d] = (w0*O0 + w1*O1) / (w0*l0 + w1*l1)
// grid (8, 24), 256 thr; thread owns one (bh, q) column (64 d values)
// ---------------------------------------------------------------------------
__global__ __launch_bounds__(256)
void combine_kernel(const unsigned short* __restrict__ P0,
                    const unsigned short* __restrict__ P1,
                    const float2* __restrict__ ML,
                    unsigned short* __restrict__ AO) {
    int bh = blockIdx.y;
    int q = blockIdx.x * 256 + threadIdx.x;
    float2 u0 = ML[(size_t)bh * 2048 + q];
    float2 u1 = ML[(size_t)(24 + bh) * 2048 + q];
    float M = fmaxf(u0.x, u1.x);
    float w0 = vexp2f(u0.x - M), w1 = vexp2f(u1.x - M);
    float inv = 1.f / (w0 * u0.y + w1 * u1.y);
    w0 *= inv; w1 *= inv;
    int b = bh / NH, h = bh % NH;
    const unsigned short* p0 = P0 + (size_t)bh * 64 * 2048 + q;
    const unsigned short* p1 = P1 + (size_t)bh * 64 * 2048 + q;
    unsigned short* dst = AO + ((size_t)(b * 2048 + q)) * DIM + h * HD;
    #pragma unroll
    for (int dc = 0; dc < 8; ++dc) {
        unsigned rr[4];
        #pragma unroll
        for (int e = 0; e < 4; ++e) {
            int d = dc * 8 + e * 2;
            float v0 = w0 * bf2f(p0[(size_t)d * 2048]) + w1 * bf2f(p1[(size_t)d * 2048]);
            float v1 = w0 * bf2f(p0[(size_t)(d + 1) * 2048]) + w1 * bf2f(p1[(size_t)(d + 1) * 2048]);
            rr[e] = cvtpk_bf16(v0, v1);
        }
        *(uint4*)(dst + dc * 8) = make_uint4(rr[0], rr[1], rr[2], rr[3]);
    }
}

// ---------------------------------------------------------------------------
extern "C" void kernel_launch(void* const* d_in, const int* in_sizes, int n_in,
                              void* d_out, int out_size, void* d_ws, size_t ws_size,
                              hipStream_t stream) {
    const float* words   = (const float*)d_in[0];
    const float* posw    = (const float*)d_in[1];
    const float* consc   = (const float*)d_in[2];
    const float* cross   = (const float*)d_in[3];
    const float* pcross  = (const float*)d_in[4];
    const float* Wq_w    = (const float*)d_in[5];
    const float* Wk_w    = (const float*)d_in[6];
    const float* Wv_w    = (const float*)d_in[7];
    const float* Wq_p    = (const float*)d_in[8];
    const float* Wk_p    = (const float*)d_in[9];
    const float* Wq_c    = (const float*)d_in[10];
    const float* Wk_c    = (const float*)d_in[11];
    const float* latentk = (const float*)d_in[12];
    const float* Wo      = (const float*)d_in[13];
    const float* bo      = (const float*)d_in[14];

    char* arena = (char*)d_ws;
    const size_t ACTB = 6291456;                 // one bf16 activation slab (bytes)
    const size_t WTE  = 768 * 768;               // elements per weight matrix
    unsigned short* S0 = (unsigned short*)(arena);            // words -> pcrossbf -> Opart1
    unsigned short* S1 = (unsigned short*)(arena + ACTB);     // posw  -> K
    unsigned short* S2 = (unsigned short*)(arena + 2 * ACTB); // consc -> Opart0
    unsigned short* S3 = (unsigned short*)(arena + 3 * ACTB); // cross -> ML
    unsigned short* WT = (unsigned short*)(arena + 4 * ACTB); // 7 x 768x768 bf16
    unsigned short* QB = WT + 7 * WTE;                        // Q bf16 -> AO
    unsigned short* VT = (unsigned short*)((char*)QB + ACTB); // V^T bf16
    float* KCV         = (float*)((char*)VT + ACTB);          // 3 KB

    float2* ML = (float2*)S3;

    // 1. activations -> bf16 (words, posw, consc, cross)
    convert_acts<<<dim3(3072, 4), dim3(256), 0, stream>>>(words, posw, consc, cross, S0);
    // 2. weights -> bf16 transposed
    conv_w<<<dim3(24, 24, 7), dim3(256), 0, stream>>>(
        Wq_w, Wq_p, Wq_c, Wk_w, Wk_p, Wv_w, Wo, WT);
    // 3. kc
    kc2_kernel<<<dim3(48), dim3(256), 0, stream>>>(latentk, Wk_c, KCV);

    // 4. fused Q + V GEMMs (768 blocks)
    GemmCfg cq = { S0, S1, S2, WT + 0 * WTE, WT + 1 * WTE, WT + 2 * WTE,
                   nullptr, QSC_LOG2E, QB, 3, 2 };
    GemmCfg cv = { S3, nullptr, nullptr, WT + 5 * WTE, nullptr, nullptr,
                   nullptr, 1.f, VT, 1, 3 };
    gemm_any<<<dim3(6, 64, 2), dim3(256), 0, stream>>>(cq, cv, 768);

    // 5. pcross -> bf16 into S0 (words dead)
    convert_acts<<<dim3(3072, 1), dim3(256), 0, stream>>>(pcross, nullptr, nullptr, nullptr, S0);

    // 6. K = cross@Wk_w + pcross@Wk_p + kc  -> S1 (posw dead)
    GemmCfg ck = { S3, S0, nullptr, WT + 3 * WTE, WT + 4 * WTE, nullptr,
                   KCV, 1.f, S1, 2, 0 };
    gemm_any<<<dim3(6, 64, 1), dim3(256), 0, stream>>>(ck, ck, 384);

    // 7. flash split-KV -> partials (S2, S0) + ML (S3)
    flash2<<<dim3(32, 24), dim3(256), 0, stream>>>(QB, S1, VT, S2, S0, ML);

    // 8. combine -> AO in QB (qb dead)
    combine_kernel<<<dim3(8, 24), dim3(256), 0, stream>>>(S2, S0, ML, QB);

    // 9. out = AO@Wo + bo (fp32)
    GemmCfg co = { QB, nullptr, nullptr, WT + 6 * WTE, nullptr, nullptr,
                   bo, 1.f, (float*)d_out, 1, 1 };
    gemm_any<<<dim3(6, 64, 1), dim3(256), 0, stream>>>(co, co, 384);
}

// Round 6
// 139.976 us; speedup vs baseline: 1.1486x; 1.1486x over previous
//
#include <hip/hip_runtime.h>
#include <math.h>

#define DIM  768
#define NH   12
#define HD   64
#define NQ   2048
#define NKV  2048
// QSCALE * log2(e) folded into Q projection epilogue
#define QSC_LOG2E 0.18033688011112042f

typedef short bf16x8  __attribute__((ext_vector_type(8)));
typedef float f32x4   __attribute__((ext_vector_type(4)));
typedef float f32x16  __attribute__((ext_vector_type(16)));

__device__ __forceinline__ unsigned short f2bf(float f) {
    unsigned u = __float_as_uint(f);
    unsigned r = (u + 0x7FFFu + ((u >> 16) & 1u)) >> 16;
    return (unsigned short)r;
}
__device__ __forceinline__ float bf2f(unsigned short u) {
    return __uint_as_float(((unsigned)u) << 16);
}

__device__ __forceinline__ unsigned cvtpk_bf16(float a, float b) {
    unsigned r;
    asm("v_cvt_pk_bf16_f32 %0, %1, %2" : "=v"(r) : "v"(a), "v"(b));
    return r;   // lo = bf16(a), hi = bf16(b)
}

// v_permlane32_swap_b32 vdst, vsrc: vdst[32..63] <-> vsrc[0..31].
__device__ __forceinline__ void plswap(unsigned& a, unsigned& b) {
    asm("v_permlane32_swap_b32 %0, %1" : "+v"(a), "+v"(b));
}

__device__ __forceinline__ float vexp2f(float x) {
#if __has_builtin(__builtin_amdgcn_exp2f)
    return __builtin_amdgcn_exp2f(x);
#else
    float r;
    asm("v_exp_f32 %0, %1\ns_nop 0" : "=v"(r) : "v"(x));
    return r;
#endif
}

__device__ __forceinline__ void ld_lds16(void* lds, const void* g) {
    __builtin_amdgcn_global_load_lds(
        (const __attribute__((address_space(1))) unsigned int*)g,
        (__attribute__((address_space(3))) unsigned int*)lds, 16, 0, 0);
}

__device__ __forceinline__ f32x16 z16() {
    f32x16 r;
    #pragma unroll
    for (int e = 0; e < 16; ++e) r[e] = 0.f;
    return r;
}

union PB16 { unsigned u[4]; bf16x8 v; };

// ---------------------------------------------------------------------------
// prep: blocks 0..4031 = weight transpose+convert (7 x 768x768 -> bf16 [n][k]);
//       blocks 4032..4079 = kc = latent @ Wk_c (fp32)
// ---------------------------------------------------------------------------
__global__ __launch_bounds__(256)
void prep_kernel(const float* __restrict__ w0, const float* __restrict__ w1,
                 const float* __restrict__ w2, const float* __restrict__ w3,
                 const float* __restrict__ w4, const float* __restrict__ w5,
                 const float* __restrict__ w6, unsigned short* __restrict__ wt,
                 const float* __restrict__ latent, const float* __restrict__ Wkc,
                 float* __restrict__ kc) {
    __shared__ float t[32][33];
    int bid = blockIdx.x;
    if (bid < 4032) {
        int iz = bid / 576, rem = bid - iz * 576;
        int iy = rem / 24, ix = rem - iy * 24;
        const float* Ws[7] = {w0, w1, w2, w3, w4, w5, w6};
        const float* W = Ws[iz];
        unsigned short* D = wt + (size_t)iz * (768 * 768);
        int r0 = iy * 32, c0 = ix * 32;
        int tx = threadIdx.x & 31, ty = threadIdx.x >> 5;
        #pragma unroll
        for (int yy = 0; yy < 4; ++yy)
            t[ty * 4 + yy][tx] = W[(size_t)(r0 + ty * 4 + yy) * 768 + c0 + tx];
        __syncthreads();
        #pragma unroll
        for (int yy = 0; yy < 4; ++yy)
            D[(size_t)(c0 + ty * 4 + yy) * 768 + r0 + tx] = f2bf(t[tx][ty * 4 + yy]);
    } else {
        int jb = bid - 4032;
        float (&red)[16][17] = *reinterpret_cast<float(*)[16][17]>(&t[0][0]);
        int tx = threadIdx.x & 15, ty = threadIdx.x >> 4;
        int j = jb * 16 + tx;
        float acc = 0.f;
        for (int i = ty * 48; i < ty * 48 + 48; ++i)
            acc += latent[i] * Wkc[i * DIM + j];
        red[ty][tx] = acc;
        __syncthreads();
        if (ty == 0) {
            float s = 0.f;
            #pragma unroll
            for (int k = 0; k < 16; ++k) s += red[k][tx];
            kc[j] = s;
        }
    }
}

// ---------------------------------------------------------------------------
// Fused Q/V/K GEMM. A = fp32 (reg-staged, cvt->swizzled LDS), B = bf16 [n][k]
// (gload_lds). Tile 64(M)x128(N), BK=64, 2-phase dbuf, 1152 blocks.
// mode: 0 bf16+bias, 2 bf16*scale, 3 bf16 transposed into Vt[b][768][2048]
// ---------------------------------------------------------------------------
struct QCfg {
    const float* A0; const float* A1; const float* A2;
    const unsigned short* B0; const unsigned short* B1; const unsigned short* B2;
    const float* bias; float scale; void* out; int npair; int mode;
};

__global__ __launch_bounds__(256)
void gemm_qvk(QCfg c0, QCfg c1, QCfg c2) {
    __shared__ unsigned short As[2][64 * 64];    // 2 x 8 KB
    __shared__ unsigned short Bs[2][128 * 64];   // 2 x 16 KB
    const int tid = threadIdx.x;
    const int w = tid >> 6, l = tid & 63, g = l >> 4, r16 = l & 15;

    // panel-aware XCD swizzle: group gidx=(z,by) pinned to xcd=gidx&7,
    // 6 bx-blocks of one A-panel contiguous on that XCD
    int p = blockIdx.x;
    int xcd = p & 7, s = p >> 3;
    int bx = s % 6, gg = s / 6;
    int gidx = gg * 8 + xcd;
    int by = gidx & 63, z = gidx >> 6;
    const int n0 = bx * 128, m0 = by * 64;

    QCfg c = (z == 0) ? c0 : (z == 1) ? c1 : c2;
    const float* Alist[3] = {c.A0, c.A1, c.A2};
    const unsigned short* Blist[3] = {c.B0, c.B1, c.B2};

    // A staging: thread -> (row ar, 16-elem col chunk at ac)
    const int ar = tid >> 2, ac = (tid & 3) * 16;
    const int aswz = (ar & 7) << 4;
    float4 av0, av1, av2, av3;

    f32x4 acc[4][2];
    #pragma unroll
    for (int i = 0; i < 4; ++i)
        #pragma unroll
        for (int j = 0; j < 2; ++j) acc[i][j] = (f32x4){0.f, 0.f, 0.f, 0.f};

#define ALOAD(AP, K0) { \
    const float* _ap = (AP) + (size_t)(m0 + ar) * 768 + (K0) + ac; \
    av0 = *(const float4*)_ap;       av1 = *(const float4*)(_ap + 4); \
    av2 = *(const float4*)(_ap + 8); av3 = *(const float4*)(_ap + 12); }

#define AWRITE(BUFI) { \
    uint4 u0_, u1_; \
    u0_.x = cvtpk_bf16(av0.x, av0.y); u0_.y = cvtpk_bf16(av0.z, av0.w); \
    u0_.z = cvtpk_bf16(av1.x, av1.y); u0_.w = cvtpk_bf16(av1.z, av1.w); \
    u1_.x = cvtpk_bf16(av2.x, av2.y); u1_.y = cvtpk_bf16(av2.z, av2.w); \
    u1_.z = cvtpk_bf16(av3.x, av3.y); u1_.w = cvtpk_bf16(av3.z, av3.w); \
    *(uint4*)((char*)As[BUFI] + ar * 128 + ((2 * ac) ^ aswz)) = u0_; \
    *(uint4*)((char*)As[BUFI] + ar * 128 + ((2 * ac + 16) ^ aswz)) = u1_; }

#define BSTAGE(BUFI, BP, K0) { _Pragma("unroll") \
    for (int is = 0; is < 4; ++is) { \
        int u = is * 256 + tid, r = u >> 3, cc = u & 7; \
        int col = ((cc ^ (r & 7)) << 3); \
        ld_lds16((char*)Bs[BUFI] + is * 4096 + w * 1024, \
                 (BP) + (size_t)(n0 + r) * 768 + (K0) + col); } }

    const int NSTEPS = c.npair * 12;
    int pn = 0, kn = 0;
    ALOAD(Alist[0], 0);
    BSTAGE(0, Blist[0], 0);
    AWRITE(0);
    kn = 64;
    __syncthreads();

    #pragma unroll 1
    for (int st = 0; st < NSTEPS; ++st) {
        int cur = st & 1;
        bool pre = (st + 1 < NSTEPS);
        if (pre) {
            ALOAD(Alist[pn], kn);
            BSTAGE(cur ^ 1, Blist[pn], kn);
        }
        const char* Ab = (const char*)As[cur];
        const char* Bb = (const char*)Bs[cur];
        #pragma unroll
        for (int kk = 0; kk < 2; ++kk) {
            bf16x8 af[4], bf[2];
            #pragma unroll
            for (int i = 0; i < 4; ++i) {
                int row = i * 16 + r16;
                af[i] = *(const bf16x8*)(Ab + row * 128 +
                          ((kk * 64 + g * 16) ^ ((row & 7) << 4)));
            }
            #pragma unroll
            for (int j = 0; j < 2; ++j) {
                int row = w * 32 + j * 16 + r16;
                bf[j] = *(const bf16x8*)(Bb + row * 128 +
                          ((kk * 64 + g * 16) ^ ((row & 7) << 4)));
            }
            #pragma unroll
            for (int i = 0; i < 4; ++i)
                #pragma unroll
                for (int j = 0; j < 2; ++j)
                    acc[i][j] = __builtin_amdgcn_mfma_f32_16x16x32_bf16(
                        af[i], bf[j], acc[i][j], 0, 0, 0);
        }
        if (pre) {
            AWRITE(cur ^ 1);
            kn += 64; if (kn == 768) { kn = 0; ++pn; }
        }
        __syncthreads();
    }
#undef ALOAD
#undef AWRITE
#undef BSTAGE

    const int mode = c.mode;
    #pragma unroll
    for (int i = 0; i < 4; ++i) {
        #pragma unroll
        for (int j = 0; j < 2; ++j) {
            int col = n0 + w * 32 + j * 16 + r16;
            float bv = (mode == 0 && c.bias) ? c.bias[col] : 0.f;
            #pragma unroll
            for (int rr = 0; rr < 4; ++rr) {
                int row = m0 + i * 16 + g * 4 + rr;
                float v = acc[i][j][rr];
                if (mode == 2) v *= c.scale;
                v += bv;
                if (mode == 3) {
                    int bb = row >> 11, q = row & 2047;
                    ((unsigned short*)c.out)[(size_t)(bb * 768 + col) * 2048 + q] = f2bf(v);
                } else {
                    ((unsigned short*)c.out)[(size_t)row * 768 + col] = f2bf(v);
                }
            }
        }
    }
}

// ---------------------------------------------------------------------------
// out = AO @ Wo + bo (fp32 out). A bf16 via gload_lds (proven path). 384 blk.
// ---------------------------------------------------------------------------
__global__ __launch_bounds__(256)
void gemm_out(const unsigned short* __restrict__ A,
              const unsigned short* __restrict__ B,
              const float* __restrict__ bias, float* __restrict__ Cout) {
    __shared__ unsigned short As[2][64 * 64];
    __shared__ unsigned short Bs[2][128 * 64];
    const int tid = threadIdx.x;
    const int w = tid >> 6, l = tid & 63, g = l >> 4, r16 = l & 15;

    int o_lin = blockIdx.x;
    int wl = (o_lin & 7) * 48 + (o_lin >> 3);
    int bx = wl % 6, by = wl / 6;
    const int n0 = bx * 128, m0 = by * 64;

    f32x4 acc[4][2];
    #pragma unroll
    for (int i = 0; i < 4; ++i)
        #pragma unroll
        for (int j = 0; j < 2; ++j) acc[i][j] = (f32x4){0.f, 0.f, 0.f, 0.f};

#define GSTAGE(BUFI, K0) { \
    _Pragma("unroll") \
    for (int is = 0; is < 2; ++is) { \
        int u = is * 256 + tid, r = u >> 3, cc = u & 7; \
        int col = ((cc ^ (r & 7)) << 3); \
        ld_lds16((char*)As[BUFI] + is * 4096 + w * 1024, \
                 A + (size_t)(m0 + r) * 768 + (K0) + col); } \
    _Pragma("unroll") \
    for (int is = 0; is < 4; ++is) { \
        int u = is * 256 + tid, r = u >> 3, cc = u & 7; \
        int col = ((cc ^ (r & 7)) << 3); \
        ld_lds16((char*)Bs[BUFI] + is * 4096 + w * 1024, \
                 B + (size_t)(n0 + r) * 768 + (K0) + col); } }

    GSTAGE(0, 0);
    __syncthreads();

    #pragma unroll 1
    for (int st = 0; st < 12; ++st) {
        int cur = st & 1;
        if (st + 1 < 12) GSTAGE(cur ^ 1, (st + 1) * 64);
        const char* Ab = (const char*)As[cur];
        const char* Bb = (const char*)Bs[cur];
        #pragma unroll
        for (int kk = 0; kk < 2; ++kk) {
            bf16x8 af[4], bf[2];
            #pragma unroll
            for (int i = 0; i < 4; ++i) {
                int row = i * 16 + r16;
                af[i] = *(const bf16x8*)(Ab + row * 128 +
                          ((kk * 64 + g * 16) ^ ((row & 7) << 4)));
            }
            #pragma unroll
            for (int j = 0; j < 2; ++j) {
                int row = w * 32 + j * 16 + r16;
                bf[j] = *(const bf16x8*)(Bb + row * 128 +
                          ((kk * 64 + g * 16) ^ ((row & 7) << 4)));
            }
            #pragma unroll
            for (int i = 0; i < 4; ++i)
                #pragma unroll
                for (int j = 0; j < 2; ++j)
                    acc[i][j] = __builtin_amdgcn_mfma_f32_16x16x32_bf16(
                        af[i], bf[j], acc[i][j], 0, 0, 0);
        }
        __syncthreads();
    }
#undef GSTAGE

    #pragma unroll
    for (int i = 0; i < 4; ++i) {
        #pragma unroll
        for (int j = 0; j < 2; ++j) {
            int col = n0 + w * 32 + j * 16 + r16;
            float bv = bias[col];
            #pragma unroll
            for (int rr = 0; rr < 4; ++rr) {
                int row = m0 + i * 16 + g * 4 + rr;
                Cout[(size_t)row * 768 + col] = acc[i][j][rr] + bv;
            }
        }
    }
}

// ---------------------------------------------------------------------------
// Flash attention, split-KV 4-way. 1536 blocks; bh-groups pinned per XCD.
// Each block: 128 q rows x 512 kv. Partials: unnormalized O bf16 [bh][q][64d]
// per part + (m,l) f32 per q-row.
// ---------------------------------------------------------------------------
__global__ __launch_bounds__(256)
void flash2(const unsigned short* __restrict__ Qb,
            const unsigned short* __restrict__ Kb,
            const unsigned short* __restrict__ Vt,
            unsigned short* __restrict__ P0, unsigned short* __restrict__ P1,
            unsigned short* __restrict__ P2, unsigned short* __restrict__ P3,
            float2* __restrict__ ML) {
    __shared__ unsigned short KV[2][2][4096];  // [buf][K|Vt][64*64], 32 KB
    const int tid = threadIdx.x;
    const int w = tid >> 6, l = tid & 63, lo = l & 31, hi = l >> 5;

    // XCD swizzle: bh -> xcd = bh&7; 64 (qi,part) blocks of a bh contiguous
    int p = blockIdx.x + 64 * blockIdx.y;   // grid (64, 24)
    int xcd = p & 7, s = p >> 3;
    int gg = s >> 6, inner = s & 63;
    int bh = gg * 8 + xcd;
    int qi = inner >> 2, part = inner & 3;
    int b = bh / NH, h = bh % NH;
    int q0 = qi * 128;
    int kvbase = part * 512;

    // Q B-fragments, scaled upstream by QSC_LOG2E
    bf16x8 qf[4];
    {
        const unsigned short* Qrow =
            Qb + (size_t)(b * NQ + q0 + w * 32 + lo) * DIM + h * HD + hi * 8;
        #pragma unroll
        for (int kc = 0; kc < 4; ++kc) qf[kc] = *(const bf16x8*)(Qrow + kc * 16);
    }

    f32x16 o0 = z16(), o1 = z16();
    float m = -3.0e38f, lsum = 0.f;

    const unsigned short* Kbase = Kb + (size_t)(b * NKV) * DIM + h * HD;
    const unsigned short* Vbase = Vt + ((size_t)b * DIM + h * HD) * NKV;

#define FSTAGE(BUFI, T0) { \
    _Pragma("unroll") \
    for (int is = 0; is < 2; ++is) { \
        int u = is * 256 + tid, r = u >> 3, cc = u & 7; \
        int col = ((cc ^ (r & 7)) << 3); \
        ld_lds16((char*)KV[BUFI][0] + is * 4096 + w * 1024, \
                 Kbase + (size_t)((T0) + r) * 768 + col); \
        ld_lds16((char*)KV[BUFI][1] + is * 4096 + w * 1024, \
                 Vbase + (size_t)r * 2048 + (T0) + col); } }

    FSTAGE(0, kvbase);
    __syncthreads();

    #pragma unroll 1
    for (int t = 0; t < 8; ++t) {
        int cur = t & 1;
        if (t < 7) FSTAGE(cur ^ 1, kvbase + (t + 1) * 64);

        const char* Kp = (const char*)KV[cur][0];
        const char* Vp = (const char*)KV[cur][1];

        // S^T = K . Q^T
        f32x16 s0 = z16(), s1 = z16();
        __builtin_amdgcn_s_setprio(1);
        #pragma unroll
        for (int kc = 0; kc < 4; ++kc) {
            int r0 = lo, r1 = 32 + lo;
            bf16x8 k0 = *(const bf16x8*)(Kp + r0 * 128 +
                          ((kc * 32 + hi * 16) ^ ((r0 & 7) << 4)));
            bf16x8 k1 = *(const bf16x8*)(Kp + r1 * 128 +
                          ((kc * 32 + hi * 16) ^ ((r1 & 7) << 4)));
            s0 = __builtin_amdgcn_mfma_f32_32x32x16_bf16(k0, qf[kc], s0, 0, 0, 0);
            s1 = __builtin_amdgcn_mfma_f32_32x32x16_bf16(k1, qf[kc], s1, 0, 0, 0);
        }
        __builtin_amdgcn_s_setprio(0);

        // in-register softmax (log2 domain); lanes (l, l^32) share a q-row
        float a8[8];
        #pragma unroll
        for (int e = 0; e < 8; ++e)
            a8[e] = fmaxf(fmaxf(fmaxf(s0[e], s0[e + 8]), s1[e]), s1[e + 8]);
        float pm = fmaxf(fmaxf(fmaxf(fmaxf(a8[0], a8[1]), fmaxf(a8[2], a8[3])),
                               fmaxf(fmaxf(a8[4], a8[5]), fmaxf(a8[6], a8[7]))), -3.0e38f);
        pm = fmaxf(pm, __shfl_xor(pm, 32));

        if (__any(pm > m + 10.f)) {           // defer-max (T13)
            float mn = fmaxf(m, pm);
            float sc = vexp2f(m - mn);
            lsum *= sc;
            #pragma unroll
            for (int e = 0; e < 16; ++e) { o0[e] *= sc; o1[e] *= sc; }
            m = mn;
        }

        #pragma unroll
        for (int e = 0; e < 16; ++e) {
            s0[e] = vexp2f(s0[e] - m);
            s1[e] = vexp2f(s1[e] - m);
        }

        float b8[8];
        #pragma unroll
        for (int e = 0; e < 8; ++e)
            b8[e] = (s0[e] + s0[e + 8]) + (s1[e] + s1[e + 8]);
        float rs = ((b8[0] + b8[1]) + (b8[2] + b8[3])) +
                   ((b8[4] + b8[5]) + (b8[6] + b8[7]));
        rs += __shfl_xor(rs, 32);
        lsum += rs;

        // P -> bf16 B-fragments via cvt_pk + permlane32_swap
        PB16 pb[4];
        #pragma unroll
        for (int cc = 0; cc < 2; ++cc) {
            unsigned a0 = cvtpk_bf16(s0[cc * 8 + 0], s0[cc * 8 + 1]);
            unsigned a1 = cvtpk_bf16(s0[cc * 8 + 2], s0[cc * 8 + 3]);
            unsigned b0 = cvtpk_bf16(s0[cc * 8 + 4], s0[cc * 8 + 5]);
            unsigned b1 = cvtpk_bf16(s0[cc * 8 + 6], s0[cc * 8 + 7]);
            plswap(a0, b0);
            plswap(a1, b1);
            pb[cc].u[0] = a0; pb[cc].u[1] = a1; pb[cc].u[2] = b0; pb[cc].u[3] = b1;
            unsigned c0 = cvtpk_bf16(s1[cc * 8 + 0], s1[cc * 8 + 1]);
            unsigned c1 = cvtpk_bf16(s1[cc * 8 + 2], s1[cc * 8 + 3]);
            unsigned d0 = cvtpk_bf16(s1[cc * 8 + 4], s1[cc * 8 + 5]);
            unsigned d1 = cvtpk_bf16(s1[cc * 8 + 6], s1[cc * 8 + 7]);
            plswap(c0, d0);
            plswap(c1, d1);
            pb[2 + cc].u[0] = c0; pb[2 + cc].u[1] = c1;
            pb[2 + cc].u[2] = d0; pb[2 + cc].u[3] = d1;
        }

        // O^T += V^T . P^T
        __builtin_amdgcn_s_setprio(1);
        #pragma unroll
        for (int c = 0; c < 4; ++c) {
            int r0 = lo, r1 = 32 + lo;
            bf16x8 v0 = *(const bf16x8*)(Vp + r0 * 128 +
                          ((c * 32 + hi * 16) ^ ((r0 & 7) << 4)));
            bf16x8 v1 = *(const bf16x8*)(Vp + r1 * 128 +
                          ((c * 32 + hi * 16) ^ ((r1 & 7) << 4)));
            o0 = __builtin_amdgcn_mfma_f32_32x32x16_bf16(v0, pb[c].v, o0, 0, 0, 0);
            o1 = __builtin_amdgcn_mfma_f32_32x32x16_bf16(v1, pb[c].v, o1, 0, 0, 0);
        }
        __builtin_amdgcn_s_setprio(0);
        __syncthreads();
    }
#undef FSTAGE

    // store unnormalized partial O bf16 as [bh][q][d] (+ (m,l) per q-row)
    unsigned short* Pp = (part == 0) ? P0 : (part == 1) ? P1 : (part == 2) ? P2 : P3;
    const int q = q0 + w * 32 + lo;
    unsigned short* Op = Pp + ((size_t)bh * 2048 + q) * 64;
    #pragma unroll
    for (int grp = 0; grp < 4; ++grp) {
        int r0 = grp * 4;
        int d0 = grp * 8 + 4 * hi;            // 4 consecutive d per group
        uint2 v0, v1;
        v0.x = cvtpk_bf16(o0[r0 + 0], o0[r0 + 1]);
        v0.y = cvtpk_bf16(o0[r0 + 2], o0[r0 + 3]);
        *(uint2*)(Op + d0) = v0;
        v1.x = cvtpk_bf16(o1[r0 + 0], o1[r0 + 1]);
        v1.y = cvtpk_bf16(o1[r0 + 2], o1[r0 + 3]);
        *(uint2*)(Op + 32 + d0) = v1;
    }
    if (hi == 0)
        ML[(size_t)(part * 24 + bh) * 2048 + q] = make_float2(m, lsum);
}

// ---------------------------------------------------------------------------
// combine 4 partials -> AO[b][q][h*64+d] bf16. grid (16, 24), 256 thr;
// thread owns (q, 32-d half); all reads/writes vectorized.
// ---------------------------------------------------------------------------
__global__ __launch_bounds__(256)
void combine4(const unsigned short* __restrict__ P0, const unsigned short* __restrict__ P1,
              const unsigned short* __restrict__ P2, const unsigned short* __restrict__ P3,
              const float2* __restrict__ ML, unsigned short* __restrict__ AO) {
    int bh = blockIdx.y;
    int idx = blockIdx.x * 256 + threadIdx.x;  // 0..4095
    int q = idx >> 1, dh = (idx & 1) * 32;

    float2 u0 = ML[(size_t)(0 * 24 + bh) * 2048 + q];
    float2 u1 = ML[(size_t)(1 * 24 + bh) * 2048 + q];
    float2 u2 = ML[(size_t)(2 * 24 + bh) * 2048 + q];
    float2 u3 = ML[(size_t)(3 * 24 + bh) * 2048 + q];
    float M = fmaxf(fmaxf(u0.x, u1.x), fmaxf(u2.x, u3.x));
    float w0 = vexp2f(u0.x - M), w1 = vexp2f(u1.x - M);
    float w2 = vexp2f(u2.x - M), w3 = vexp2f(u3.x - M);
    float inv = 1.f / (w0 * u0.y + w1 * u1.y + w2 * u2.y + w3 * u3.y);
    w0 *= inv; w1 *= inv; w2 *= inv; w3 *= inv;

    size_t off = ((size_t)bh * 2048 + q) * 64 + dh;
    float acc[32];
    #pragma unroll
    for (int e = 0; e < 32; ++e) acc[e] = 0.f;
    const unsigned short* Ps[4] = {P0, P1, P2, P3};
    float ws[4] = {w0, w1, w2, w3};
    #pragma unroll
    for (int pp = 0; pp < 4; ++pp) {
        const unsigned short* src = Ps[pp] + off;
        float wv = ws[pp];
        #pragma unroll
        for (int c = 0; c < 4; ++c) {
            ushort4 hh2;
            uint4 vv = *(const uint4*)(src + c * 8);
            unsigned uu[4] = {vv.x, vv.y, vv.z, vv.w};
            #pragma unroll
            for (int e = 0; e < 4; ++e) {
                acc[c * 8 + e * 2 + 0] += wv * bf2f((unsigned short)(uu[e] & 0xFFFF));
                acc[c * 8 + e * 2 + 1] += wv * bf2f((unsigned short)(uu[e] >> 16));
            }
            (void)hh2;
        }
    }
    int b = bh / NH, h = bh % NH;
    unsigned short* dst = AO + ((size_t)(b * 2048 + q)) * DIM + h * HD + dh;
    #pragma unroll
    for (int c = 0; c < 4; ++c) {
        uint4 ov;
        ov.x = cvtpk_bf16(acc[c * 8 + 0], acc[c * 8 + 1]);
        ov.y = cvtpk_bf16(acc[c * 8 + 2], acc[c * 8 + 3]);
        ov.z = cvtpk_bf16(acc[c * 8 + 4], acc[c * 8 + 5]);
        ov.w = cvtpk_bf16(acc[c * 8 + 6], acc[c * 8 + 7]);
        *(uint4*)(dst + c * 8) = ov;
    }
}

// ---------------------------------------------------------------------------
extern "C" void kernel_launch(void* const* d_in, const int* in_sizes, int n_in,
                              void* d_out, int out_size, void* d_ws, size_t ws_size,
                              hipStream_t stream) {
    const float* words   = (const float*)d_in[0];
    const float* posw    = (const float*)d_in[1];
    const float* consc   = (const float*)d_in[2];
    const float* cross   = (const float*)d_in[3];
    const float* pcross  = (const float*)d_in[4];
    const float* Wq_w    = (const float*)d_in[5];
    const float* Wk_w    = (const float*)d_in[6];
    const float* Wv_w    = (const float*)d_in[7];
    const float* Wq_p    = (const float*)d_in[8];
    const float* Wk_p    = (const float*)d_in[9];
    const float* Wq_c    = (const float*)d_in[10];
    const float* Wk_c    = (const float*)d_in[11];
    const float* latentk = (const float*)d_in[12];
    const float* Wo      = (const float*)d_in[13];
    const float* bo      = (const float*)d_in[14];

    char* arena = (char*)d_ws;
    const size_t WTE = 768 * 768;                       // elems per weight
    unsigned short* WT = (unsigned short*)(arena);      // 7 x 1,179,648 B
    unsigned short* QB = (unsigned short*)(arena + 8257536);
    unsigned short* VT = (unsigned short*)(arena + 14548992);
    unsigned short* KB = (unsigned short*)(arena + 20840448);
    unsigned short* P0 = (unsigned short*)(arena + 27131904);
    unsigned short* P1 = (unsigned short*)(arena + 33423360);
    unsigned short* P2 = (unsigned short*)(arena + 39714816);
    unsigned short* P3 = (unsigned short*)(arena);      // overlays WT[0..5] (dead in flash)
    float2* ML         = (float2*)(arena + 46006272);   // 1,572,864 B
    float* KCV         = (float*)(arena + 47579136);    // 3 KB; total 47.58 MB

    // 1. prep: weights -> bf16 [n][k] + kc
    prep_kernel<<<dim3(4080), dim3(256), 0, stream>>>(
        Wq_w, Wq_p, Wq_c, Wk_w, Wk_p, Wv_w, Wo, WT, latentk, Wk_c, KCV);

    // 2. fused Q/V/K GEMMs straight from fp32 activations
    QCfg cq = { words, posw, consc,
                WT + 0 * WTE, WT + 1 * WTE, WT + 2 * WTE,
                nullptr, QSC_LOG2E, QB, 3, 2 };
    QCfg cv = { cross, nullptr, nullptr,
                WT + 5 * WTE, nullptr, nullptr,
                nullptr, 1.f, VT, 1, 3 };
    QCfg ck = { cross, pcross, nullptr,
                WT + 3 * WTE, WT + 4 * WTE, nullptr,
                KCV, 1.f, KB, 2, 0 };
    gemm_qvk<<<dim3(1152), dim3(256), 0, stream>>>(cq, cv, ck);

    // 3. flash split-KV 4-way
    flash2<<<dim3(64, 24), dim3(256), 0, stream>>>(QB, KB, VT, P0, P1, P2, P3, ML);

    // 4. combine -> AO (into QB; Q dead)
    combine4<<<dim3(16, 24), dim3(256), 0, stream>>>(P0, P1, P2, P3, ML, QB);

    // 5. out = AO @ Wo + bo (fp32)
    gemm_out<<<dim3(384), dim3(256), 0, stream>>>(QB, WT + 6 * WTE, bo, (float*)d_out);
}